// Round 4
// baseline (848.713 us; speedup 1.0000x reference)
//
#include <hip/hip_runtime.h>
#include <stdint.h>

#define BATCH 128
#define SEQL  512
#define FDIM  768
#define CTAGS 52
#define START_IDX 50
#define STOP_IDX  51
#define NEG_INF (-3.0e38f)

// ---------------------------------------------------------------------------
// K0: transpose W [52][768] -> WT [768][52] (k-major, 16B-aligned rows since
// 52*4B = 208 = 13*16). Tiny (160 KB), runs once.
// ---------------------------------------------------------------------------
__global__ __launch_bounds__(256) void wtrans(
    const float* __restrict__ W, float* __restrict__ WT)
{
    int idx = blockIdx.x * 256 + threadIdx.x;
    if (idx < FDIM * CTAGS) {
        int k = idx / CTAGS;
        int c = idx - k * CTAGS;
        WT[idx] = W[(size_t)c * FDIM + k];
    }
}

// ---------------------------------------------------------------------------
// K1: emission GEMM, lane = row. F per-lane vector loads (192 MB streamed
// through the vector path). W^T broadcast per k: the opaque-zero VGPR added
// to the base defeats scalarization, forcing global_load_dwordx4; at runtime
// all 64 lanes hit the same address -> coalesced single L1-hit request.
// Zero N-padding waste, zero LDS, no barriers. FMA floor = 33 us.
// ---------------------------------------------------------------------------
__global__ __launch_bounds__(256, 4) void emit_gemm3(
    const float* __restrict__ F, const float* __restrict__ WT,
    const float* __restrict__ bias, float* __restrict__ emit)
{
    const int lane = threadIdx.x & 63;
    const int wv   = threadIdx.x >> 6;
    const int row  = (blockIdx.x * 4 + wv) * 64 + lane;

    // opaque zero in a VGPR: compiler cannot prove uniformity -> vector loads
    int z;
    asm volatile("v_mov_b32 %0, 0" : "=v"(z));
    const float* WTz = WT + z;

    float acc[CTAGS];
#pragma unroll
    for (int c = 0; c < CTAGS; ++c) acc[c] = bias[c];

    const float* fp = F + (size_t)row * FDIM;

    for (int k0 = 0; k0 < FDIM; k0 += 8) {
        float4 fa = *(const float4*)(fp + k0);
        float4 fb = *(const float4*)(fp + k0 + 4);
        float f[8] = {fa.x, fa.y, fa.z, fa.w, fb.x, fb.y, fb.z, fb.w};
#pragma unroll
        for (int kk = 0; kk < 8; ++kk) {
            const float* wk = WTz + (size_t)(k0 + kk) * CTAGS;
#pragma unroll
            for (int q = 0; q < 13; ++q) {
                float4 w = *(const float4*)(wk + q * 4);
                acc[q * 4 + 0] = fmaf(f[kk], w.x, acc[q * 4 + 0]);
                acc[q * 4 + 1] = fmaf(f[kk], w.y, acc[q * 4 + 1]);
                acc[q * 4 + 2] = fmaf(f[kk], w.z, acc[q * 4 + 2]);
                acc[q * 4 + 3] = fmaf(f[kk], w.w, acc[q * 4 + 3]);
            }
        }
    }

    float* eo = emit + (size_t)row * CTAGS;
#pragma unroll
    for (int q = 0; q < 13; ++q)
        *(float4*)(eo + q * 4) =
            make_float4(acc[q * 4], acc[q * 4 + 1], acc[q * 4 + 2], acc[q * 4 + 3]);
}

// ---------------------------------------------------------------------------
// K2: serial Viterbi scan, max value only (unchanged, known-good).
// ---------------------------------------------------------------------------
__global__ __launch_bounds__(64) void viterbi_scan(
    const float* __restrict__ emit, const int* __restrict__ masks,
    const float* __restrict__ T, float* __restrict__ s_hist,
    float* __restrict__ out, int* __restrict__ btag)
{
    const int b  = blockIdx.x;
    const int to = threadIdx.x;
    const int toc = (to < CTAGS) ? to : (CTAGS - 1);

    float Trow[CTAGS];
#pragma unroll
    for (int f = 0; f < CTAGS; ++f) Trow[f] = T[toc * CTAGS + f];
    const float tstop = T[STOP_IDX * CTAGS + toc];

    const float* eb = emit   + (size_t)b * SEQL * CTAGS;
    const int*   mb = masks  + (size_t)b * SEQL;
    float*       sb = s_hist + (size_t)b * SEQL * CTAGS;

    float cur   = (to == START_IDX) ? 0.f : -10000.f;
    float e_cur = eb[toc];
    int   m_cur = mb[0];

    for (int t = 0; t < SEQL; ++t) {
        float e_nxt = 0.f;
        int   m_nxt = 0;
        if (t + 1 < SEQL) {
            e_nxt = eb[(size_t)(t + 1) * CTAGS + toc];
            m_nxt = mb[t + 1];
        }

        if (to < CTAGS) sb[(size_t)t * CTAGS + to] = cur;

        const unsigned cu = __float_as_uint(cur);
        float a[CTAGS];
#pragma unroll
        for (int f = 0; f < CTAGS; ++f)
            a[f] = __uint_as_float(__builtin_amdgcn_readlane((int)cu, f)) + Trow[f];

        float l1[17];
#pragma unroll
        for (int i = 0; i < 17; ++i)
            l1[i] = fmaxf(fmaxf(a[3 * i], a[3 * i + 1]), a[3 * i + 2]);
        float l2[6];
#pragma unroll
        for (int i = 0; i < 5; ++i)
            l2[i] = fmaxf(fmaxf(l1[3 * i], l1[3 * i + 1]), l1[3 * i + 2]);
        l2[5] = fmaxf(fmaxf(l1[15], l1[16]), a[51]);
        const float m = fmaxf(fmaxf(fmaxf(l2[0], l2[1]), l2[2]),
                              fmaxf(fmaxf(l2[3], l2[4]), l2[5]));

        cur   = m_cur ? (m + e_cur) : cur;
        e_cur = e_nxt;
        m_cur = m_nxt;
    }

    float v   = (to < CTAGS) ? (cur + tstop) : NEG_INF;
    int  bidx = to;
#pragma unroll
    for (int s = 1; s < 64; s <<= 1) {
        float ov = __shfl_xor(v, s);
        int   oi = __shfl_xor(bidx, s);
        if (ov > v || (ov == v && oi < bidx)) { v = ov; bidx = oi; }
    }
    if (to == 0) { out[b] = v; btag[b] = bidx; }
}

// ---------------------------------------------------------------------------
// K3: backpointers, parallel over (b,t). (unchanged, known-good)
// ---------------------------------------------------------------------------
#define PPW 16

__global__ __launch_bounds__(256) void bp_compute(
    const float* __restrict__ s_hist, const float* __restrict__ T,
    unsigned char* __restrict__ bp)
{
    const int lane = threadIdx.x & 63;
    const int wv   = __builtin_amdgcn_readfirstlane(threadIdx.x >> 6);
    const int toc  = (lane < CTAGS) ? lane : (CTAGS - 1);
    const int w    = blockIdx.x * 4 + wv;

    float Trow[CTAGS];
#pragma unroll
    for (int f = 0; f < CTAGS; ++f) Trow[f] = T[toc * CTAGS + f];

    for (int i = 0; i < PPW; ++i) {
        const int p = w * PPW + i;            // p = b*SEQL + t
        const float* sp = s_hist + (size_t)p * CTAGS;

        float a[CTAGS];
#pragma unroll
        for (int q = 0; q < 13; ++q) {
            float4 sv = *(const float4*)(sp + q * 4);
            a[q * 4 + 0] = sv.x + Trow[q * 4 + 0];
            a[q * 4 + 1] = sv.y + Trow[q * 4 + 1];
            a[q * 4 + 2] = sv.z + Trow[q * 4 + 2];
            a[q * 4 + 3] = sv.w + Trow[q * 4 + 3];
        }

        float l1[17];
#pragma unroll
        for (int j = 0; j < 17; ++j)
            l1[j] = fmaxf(fmaxf(a[3 * j], a[3 * j + 1]), a[3 * j + 2]);
        float l2[6];
#pragma unroll
        for (int j = 0; j < 5; ++j)
            l2[j] = fmaxf(fmaxf(l1[3 * j], l1[3 * j + 1]), l1[3 * j + 2]);
        l2[5] = fmaxf(fmaxf(l1[15], l1[16]), a[51]);
        const float m = fmaxf(fmaxf(fmaxf(l2[0], l2[1]), l2[2]),
                              fmaxf(fmaxf(l2[3], l2[4]), l2[5]));

        int c1[18];
#pragma unroll
        for (int j = 0; j < 17; ++j) {
            int x = (a[3 * j]     == m) ? (3 * j)     : 63;
            int y = (a[3 * j + 1] == m) ? (3 * j + 1) : 63;
            int z = (a[3 * j + 2] == m) ? (3 * j + 2) : 63;
            c1[j] = min(min(x, y), z);
        }
        c1[17] = (a[51] == m) ? 51 : 63;
        int c2[6];
#pragma unroll
        for (int j = 0; j < 6; ++j)
            c2[j] = min(min(c1[3 * j], c1[3 * j + 1]), c1[3 * j + 2]);
        const int idx = min(min(min(c2[0], c2[1]), c2[2]),
                            min(min(c2[3], c2[4]), c2[5]));

        if (lane < CTAGS)
            bp[(size_t)p * CTAGS + lane] = (unsigned char)idx;
    }
}

// ---------------------------------------------------------------------------
// K4: backtrack (unchanged, known-good).
// ---------------------------------------------------------------------------
__global__ __launch_bounds__(64) void viterbi_bt(
    const unsigned char* __restrict__ bp, const int* __restrict__ masks,
    const int* __restrict__ btag, float* __restrict__ out)
{
    const int b   = blockIdx.x;
    const int tid = threadIdx.x;

    __shared__ __align__(16) unsigned char bpl[SEQL * CTAGS];
    __shared__ int ml[SEQL];
    __shared__ unsigned char pathb[SEQL];

    const uint4* src = (const uint4*)(bp + (size_t)b * SEQL * CTAGS);
    for (int i = tid; i < SEQL * CTAGS / 16; i += 64)
        ((uint4*)bpl)[i] = src[i];
    for (int i = tid; i < SEQL; i += 64) ml[i] = masks[(size_t)b * SEQL + i];
    __syncthreads();

    int c = btag[b];
    if (tid == 0) pathb[SEQL - 1] = (unsigned char)c;
    for (int i = SEQL - 2; i >= 0; --i) {
        int nxt = bpl[(i + 1) * CTAGS + c];
        c = ml[i] ? nxt : c;
        if (tid == 0) pathb[i] = (unsigned char)c;
    }
    __syncthreads();

    float* po = out + BATCH + (size_t)b * SEQL;
#pragma unroll
    for (int i = 0; i < 8; ++i)
        po[i * 64 + tid] = (float)pathb[i * 64 + tid];
}

// ---------------------------------------------------------------------------
extern "C" void kernel_launch(void* const* d_in, const int* in_sizes, int n_in,
                              void* d_out, int out_size, void* d_ws, size_t ws_size,
                              hipStream_t stream)
{
    const float* features = (const float*)d_in[0];
    const int*   masks    = (const int*)d_in[1];
    const float* W        = (const float*)d_in[2];
    const float* bias     = (const float*)d_in[3];
    const float* T        = (const float*)d_in[4];

    float* out = (float*)d_out;

    // ws layout: emit/s_hist (13.63 MB, aliased) | bp (3.41 MB) | btag
    // WT (160 KB) aliases the bp region: written before emit_gemm3, dead
    // before bp_compute overwrites it (stream-ordered).
    const size_t emit_bytes = (size_t)BATCH * SEQL * CTAGS * sizeof(float);
    const size_t bp_bytes   = (size_t)BATCH * SEQL * CTAGS;
    float*         emit   = (float*)d_ws;
    float*         s_hist = emit;
    unsigned char* bpws   = (unsigned char*)d_ws + emit_bytes;
    float*         WT     = (float*)bpws;
    int*           btag   = (int*)((unsigned char*)d_ws + emit_bytes + bp_bytes);

    wtrans<<<(FDIM * CTAGS + 255) / 256, 256, 0, stream>>>(W, WT);
    emit_gemm3<<<BATCH * SEQL / 256, 256, 0, stream>>>(features, WT, bias, emit);
    viterbi_scan<<<BATCH, 64, 0, stream>>>(emit, masks, T, s_hist, out, btag);
    bp_compute<<<BATCH * SEQL / (4 * PPW), 256, 0, stream>>>(s_hist, T, bpws);
    viterbi_bt<<<BATCH, 64, 0, stream>>>(bpws, masks, btag, out);
}

// Round 5
// 386.755 us; speedup vs baseline: 2.1944x; 2.1944x over previous
//
#include <hip/hip_runtime.h>
#include <stdint.h>

#define BATCH 128
#define SEQL  512
#define FDIM  768
#define CTAGS 52
#define START_IDX 50
#define STOP_IDX  51
#define NEG_INF (-3.0e38f)

// ---------------------------------------------------------------------------
// K0: transpose W [52][768] -> WT [768][52]. Tiny, runs once.
// ---------------------------------------------------------------------------
__global__ __launch_bounds__(256) void wtrans(
    const float* __restrict__ W, float* __restrict__ WT)
{
    int idx = blockIdx.x * 256 + threadIdx.x;
    if (idx < FDIM * CTAGS) {
        int k = idx / CTAGS;
        int c = idx - k * CTAGS;
        WT[idx] = W[(size_t)c * FDIM + k];
    }
}

// ---------------------------------------------------------------------------
// K1: emission GEMM. Block = 64 rows x 52 cols, 256 threads = 4 waves.
// Wave w owns col group [13w, 13w+13); lane = row. 13 accumulators/lane.
// W goes through the SCALAR path (wave-uniform address -> s_load, 160 KB
// total, exactly what the constant path is for); FMA uses the SGPR operand.
// F goes through the VECTOR path: coalesced global float4 loads staged into
// LDS with padded row stride 33 floats (<=2-way bank conflicts = free),
// double-buffered with ONE barrier per BK=32 tile.
// Grid = 1024 blocks -> 4 blocks/CU, 16 waves/CU (fixes R4's 1-wave/SIMD).
// ---------------------------------------------------------------------------
#define BK32 32
#define LPAD 33   // padded row stride in floats

__global__ __launch_bounds__(256) void emit_gemm4(
    const float* __restrict__ F, const float* __restrict__ WT,
    const float* __restrict__ bias, float* __restrict__ emit)
{
    __shared__ float buf[2][64 * LPAD];   // 2 x 8448 B = 16.9 KB

    const int tid  = threadIdx.x;
    const int lane = tid & 63;
    const int cg   = __builtin_amdgcn_readfirstlane(tid >> 6);  // 0..3
    const int c0   = cg * 13;
    const int row0 = blockIdx.x * 64;

    // staging map: thread covers chunks tid and tid+256 of the 64x32 tile
    const int r0 = tid >> 3;          // 0..31
    const int s0 = tid & 7;           // 0..7 (float4 slot)
    const float* g0 = F + (size_t)(row0 + r0) * FDIM + s0 * 4;
    const float* g1 = g0 + (size_t)32 * FDIM;
    const int i0 = r0 * LPAD + s0 * 4;
    const int i1 = (r0 + 32) * LPAD + s0 * 4;

    float acc[13];
#pragma unroll
    for (int c = 0; c < 13; ++c) acc[c] = bias[c0 + c];  // uniform -> s_load

    // prologue: stage tile 0 into buf[0]
    {
        float4 a0 = *(const float4*)g0;
        float4 a1 = *(const float4*)g1;
        buf[0][i0 + 0] = a0.x; buf[0][i0 + 1] = a0.y;
        buf[0][i0 + 2] = a0.z; buf[0][i0 + 3] = a0.w;
        buf[0][i1 + 0] = a1.x; buf[0][i1 + 1] = a1.y;
        buf[0][i1 + 2] = a1.z; buf[0][i1 + 3] = a1.w;
    }
    __syncthreads();

    int cur = 0;
    for (int t = 0; t < FDIM / BK32; ++t) {
        const int k0 = t * BK32;

        // prefetch next tile to VGPRs (latency hides under compute)
        float4 b0, b1;
        if (t < FDIM / BK32 - 1) {
            b0 = *(const float4*)(g0 + k0 + BK32);
            b1 = *(const float4*)(g1 + k0 + BK32);
        }

        // compute on buf[cur]
        const float* fb = &buf[cur][lane * LPAD];
#pragma unroll
        for (int kk = 0; kk < BK32; kk += 4) {
            float f0 = fb[kk + 0], f1 = fb[kk + 1];
            float f2 = fb[kk + 2], f3 = fb[kk + 3];
            const float* w0 = WT + (size_t)(k0 + kk + 0) * CTAGS + c0;
            const float* w1 = WT + (size_t)(k0 + kk + 1) * CTAGS + c0;
            const float* w2 = WT + (size_t)(k0 + kk + 2) * CTAGS + c0;
            const float* w3 = WT + (size_t)(k0 + kk + 3) * CTAGS + c0;
#pragma unroll
            for (int c = 0; c < 13; ++c) {
                acc[c] = fmaf(f0, w0[c], acc[c]);
                acc[c] = fmaf(f1, w1[c], acc[c]);
                acc[c] = fmaf(f2, w2[c], acc[c]);
                acc[c] = fmaf(f3, w3[c], acc[c]);
            }
        }

        // write next tile into the other buffer; single barrier per tile.
        // Safe: everyone finished reading buf[cur^1] before the PREVIOUS
        // barrier (it was 'cur' of iteration t-1).
        if (t < FDIM / BK32 - 1) {
            buf[cur ^ 1][i0 + 0] = b0.x; buf[cur ^ 1][i0 + 1] = b0.y;
            buf[cur ^ 1][i0 + 2] = b0.z; buf[cur ^ 1][i0 + 3] = b0.w;
            buf[cur ^ 1][i1 + 0] = b1.x; buf[cur ^ 1][i1 + 1] = b1.y;
            buf[cur ^ 1][i1 + 2] = b1.z; buf[cur ^ 1][i1 + 3] = b1.w;
        }
        __syncthreads();
        cur ^= 1;
    }

    // store 13 floats per lane (rows 16B-aligned but col offset 52B: scalar
    // stores; total write is only 13.6 MB)
    float* eo = emit + (size_t)(row0 + lane) * CTAGS + c0;
#pragma unroll
    for (int c = 0; c < 13; ++c) eo[c] = acc[c];
}

// ---------------------------------------------------------------------------
// K2: serial Viterbi scan, max value only (unchanged, known-good).
// ---------------------------------------------------------------------------
__global__ __launch_bounds__(64) void viterbi_scan(
    const float* __restrict__ emit, const int* __restrict__ masks,
    const float* __restrict__ T, float* __restrict__ s_hist,
    float* __restrict__ out, int* __restrict__ btag)
{
    const int b  = blockIdx.x;
    const int to = threadIdx.x;
    const int toc = (to < CTAGS) ? to : (CTAGS - 1);

    float Trow[CTAGS];
#pragma unroll
    for (int f = 0; f < CTAGS; ++f) Trow[f] = T[toc * CTAGS + f];
    const float tstop = T[STOP_IDX * CTAGS + toc];

    const float* eb = emit   + (size_t)b * SEQL * CTAGS;
    const int*   mb = masks  + (size_t)b * SEQL;
    float*       sb = s_hist + (size_t)b * SEQL * CTAGS;

    float cur   = (to == START_IDX) ? 0.f : -10000.f;
    float e_cur = eb[toc];
    int   m_cur = mb[0];

    for (int t = 0; t < SEQL; ++t) {
        float e_nxt = 0.f;
        int   m_nxt = 0;
        if (t + 1 < SEQL) {
            e_nxt = eb[(size_t)(t + 1) * CTAGS + toc];
            m_nxt = mb[t + 1];
        }

        if (to < CTAGS) sb[(size_t)t * CTAGS + to] = cur;

        const unsigned cu = __float_as_uint(cur);
        float a[CTAGS];
#pragma unroll
        for (int f = 0; f < CTAGS; ++f)
            a[f] = __uint_as_float(__builtin_amdgcn_readlane((int)cu, f)) + Trow[f];

        float l1[17];
#pragma unroll
        for (int i = 0; i < 17; ++i)
            l1[i] = fmaxf(fmaxf(a[3 * i], a[3 * i + 1]), a[3 * i + 2]);
        float l2[6];
#pragma unroll
        for (int i = 0; i < 5; ++i)
            l2[i] = fmaxf(fmaxf(l1[3 * i], l1[3 * i + 1]), l1[3 * i + 2]);
        l2[5] = fmaxf(fmaxf(l1[15], l1[16]), a[51]);
        const float m = fmaxf(fmaxf(fmaxf(l2[0], l2[1]), l2[2]),
                              fmaxf(fmaxf(l2[3], l2[4]), l2[5]));

        cur   = m_cur ? (m + e_cur) : cur;
        e_cur = e_nxt;
        m_cur = m_nxt;
    }

    float v   = (to < CTAGS) ? (cur + tstop) : NEG_INF;
    int  bidx = to;
#pragma unroll
    for (int s = 1; s < 64; s <<= 1) {
        float ov = __shfl_xor(v, s);
        int   oi = __shfl_xor(bidx, s);
        if (ov > v || (ov == v && oi < bidx)) { v = ov; bidx = oi; }
    }
    if (to == 0) { out[b] = v; btag[b] = bidx; }
}

// ---------------------------------------------------------------------------
// K3: backpointers, parallel over (b,t). (unchanged, known-good)
// ---------------------------------------------------------------------------
#define PPW 16

__global__ __launch_bounds__(256) void bp_compute(
    const float* __restrict__ s_hist, const float* __restrict__ T,
    unsigned char* __restrict__ bp)
{
    const int lane = threadIdx.x & 63;
    const int wv   = __builtin_amdgcn_readfirstlane(threadIdx.x >> 6);
    const int toc  = (lane < CTAGS) ? lane : (CTAGS - 1);
    const int w    = blockIdx.x * 4 + wv;

    float Trow[CTAGS];
#pragma unroll
    for (int f = 0; f < CTAGS; ++f) Trow[f] = T[toc * CTAGS + f];

    for (int i = 0; i < PPW; ++i) {
        const int p = w * PPW + i;            // p = b*SEQL + t
        const float* sp = s_hist + (size_t)p * CTAGS;

        float a[CTAGS];
#pragma unroll
        for (int q = 0; q < 13; ++q) {
            float4 sv = *(const float4*)(sp + q * 4);
            a[q * 4 + 0] = sv.x + Trow[q * 4 + 0];
            a[q * 4 + 1] = sv.y + Trow[q * 4 + 1];
            a[q * 4 + 2] = sv.z + Trow[q * 4 + 2];
            a[q * 4 + 3] = sv.w + Trow[q * 4 + 3];
        }

        float l1[17];
#pragma unroll
        for (int j = 0; j < 17; ++j)
            l1[j] = fmaxf(fmaxf(a[3 * j], a[3 * j + 1]), a[3 * j + 2]);
        float l2[6];
#pragma unroll
        for (int j = 0; j < 5; ++j)
            l2[j] = fmaxf(fmaxf(l1[3 * j], l1[3 * j + 1]), l1[3 * j + 2]);
        l2[5] = fmaxf(fmaxf(l1[15], l1[16]), a[51]);
        const float m = fmaxf(fmaxf(fmaxf(l2[0], l2[1]), l2[2]),
                              fmaxf(fmaxf(l2[3], l2[4]), l2[5]));

        int c1[18];
#pragma unroll
        for (int j = 0; j < 17; ++j) {
            int x = (a[3 * j]     == m) ? (3 * j)     : 63;
            int y = (a[3 * j + 1] == m) ? (3 * j + 1) : 63;
            int z = (a[3 * j + 2] == m) ? (3 * j + 2) : 63;
            c1[j] = min(min(x, y), z);
        }
        c1[17] = (a[51] == m) ? 51 : 63;
        int c2[6];
#pragma unroll
        for (int j = 0; j < 6; ++j)
            c2[j] = min(min(c1[3 * j], c1[3 * j + 1]), c1[3 * j + 2]);
        const int idx = min(min(min(c2[0], c2[1]), c2[2]),
                            min(min(c2[3], c2[4]), c2[5]));

        if (lane < CTAGS)
            bp[(size_t)p * CTAGS + lane] = (unsigned char)idx;
    }
}

// ---------------------------------------------------------------------------
// K4: backtrack (unchanged, known-good).
// ---------------------------------------------------------------------------
__global__ __launch_bounds__(64) void viterbi_bt(
    const unsigned char* __restrict__ bp, const int* __restrict__ masks,
    const int* __restrict__ btag, float* __restrict__ out)
{
    const int b   = blockIdx.x;
    const int tid = threadIdx.x;

    __shared__ __align__(16) unsigned char bpl[SEQL * CTAGS];
    __shared__ int ml[SEQL];
    __shared__ unsigned char pathb[SEQL];

    const uint4* src = (const uint4*)(bp + (size_t)b * SEQL * CTAGS);
    for (int i = tid; i < SEQL * CTAGS / 16; i += 64)
        ((uint4*)bpl)[i] = src[i];
    for (int i = tid; i < SEQL; i += 64) ml[i] = masks[(size_t)b * SEQL + i];
    __syncthreads();

    int c = btag[b];
    if (tid == 0) pathb[SEQL - 1] = (unsigned char)c;
    for (int i = SEQL - 2; i >= 0; --i) {
        int nxt = bpl[(i + 1) * CTAGS + c];
        c = ml[i] ? nxt : c;
        if (tid == 0) pathb[i] = (unsigned char)c;
    }
    __syncthreads();

    float* po = out + BATCH + (size_t)b * SEQL;
#pragma unroll
    for (int i = 0; i < 8; ++i)
        po[i * 64 + tid] = (float)pathb[i * 64 + tid];
}

// ---------------------------------------------------------------------------
extern "C" void kernel_launch(void* const* d_in, const int* in_sizes, int n_in,
                              void* d_out, int out_size, void* d_ws, size_t ws_size,
                              hipStream_t stream)
{
    const float* features = (const float*)d_in[0];
    const int*   masks    = (const int*)d_in[1];
    const float* W        = (const float*)d_in[2];
    const float* bias     = (const float*)d_in[3];
    const float* T        = (const float*)d_in[4];

    float* out = (float*)d_out;

    // ws layout: emit/s_hist (13.63 MB, aliased) | bp (3.41 MB) | btag
    // WT (160 KB) aliases the bp region: written before emit_gemm4, dead
    // before bp_compute overwrites it (stream-ordered).
    const size_t emit_bytes = (size_t)BATCH * SEQL * CTAGS * sizeof(float);
    const size_t bp_bytes   = (size_t)BATCH * SEQL * CTAGS;
    float*         emit   = (float*)d_ws;
    float*         s_hist = emit;
    unsigned char* bpws   = (unsigned char*)d_ws + emit_bytes;
    float*         WT     = (float*)bpws;
    int*           btag   = (int*)((unsigned char*)d_ws + emit_bytes + bp_bytes);

    wtrans<<<(FDIM * CTAGS + 255) / 256, 256, 0, stream>>>(W, WT);
    emit_gemm4<<<BATCH * SEQL / 64, 256, 0, stream>>>(features, WT, bias, emit);
    viterbi_scan<<<BATCH, 64, 0, stream>>>(emit, masks, T, s_hist, out, btag);
    bp_compute<<<BATCH * SEQL / (4 * PPW), 256, 0, stream>>>(s_hist, T, bpws);
    viterbi_bt<<<BATCH, 64, 0, stream>>>(bpws, masks, btag, out);
}